// Round 10
// baseline (596.579 us; speedup 1.0000x reference)
//
#include <hip/hip_runtime.h>
#include <hip/hip_bf16.h>
#include <stdint.h>

#define NA 500000
#define NB 500000
#define EE 1000000
#define NBUCK 3907          // ceil(500000/128)
// Per-XCD slice capacities. 8 slices per bucket.
#define SCAPA 88            // 8*88  = 704 entries/bucket
#define SCAPB 50            // 8*50  = 400 entries/bucket
#define OCAP 2048

typedef __attribute__((ext_vector_type(8))) short bf16x8;
typedef __attribute__((ext_vector_type(4))) float f32x4;
#define MFMA16 __builtin_amdgcn_mfma_f32_16x16x32_bf16

__device__ __forceinline__ uint32_t f2bf(float f) {
    uint32_t b = __builtin_bit_cast(uint32_t, f);
    return (b + 0x7FFFu + ((b >> 16) & 1u)) >> 16;  // RNE
}
__device__ __forceinline__ float bf2f(uint32_t h) {
    return __builtin_bit_cast(float, h << 16);
}

__device__ __forceinline__ int xcc_id() {
    int x;
    asm("s_getreg_b32 %0, hwreg(HW_REG_XCC_ID)" : "=s"(x));
    return x & 7;
}

// ---- K1: bucket scatter, XCD-sliced. entry = src | type<<19 | dstLocal<<20 ----
// Entry stores via atomicExch: executes at the local XCD's L2 and allocates
// the line there, so 16 entries/line merge and write back once (plain dword
// stores were write-no-allocate -> 3M x ~32B partial writes = 106MB observed).
__global__ __launch_bounds__(256) void bucket_scatter(
    const int* __restrict__ ei_ab, const int* __restrict__ ei_ba,
    const int* __restrict__ ei_aa,
    int* __restrict__ cnt_a, int* __restrict__ cnt_b,
    uint32_t* __restrict__ buck_a, uint32_t* __restrict__ buck_b,
    int* __restrict__ ocnt, uint2* __restrict__ oflow) {
    const int xcd = xcc_id();
    int gid = blockIdx.x * 256 + threadIdx.x;
    if (gid >= 3 * EE) return;
    int dst, src, type, famA;
    if (gid < EE) {
        dst = ei_ab[EE + gid]; src = ei_ab[gid]; type = 0; famA = 0;
    } else if (gid < 2 * EE) {
        int e = gid - EE;
        dst = ei_ba[EE + e]; src = ei_ba[e]; type = 0; famA = 1;
    } else {
        int e = gid - 2 * EE;
        dst = ei_aa[EE + e]; src = ei_aa[e]; type = 1; famA = 1;
    }
    int bucket = dst >> 7;
    uint32_t entry = (uint32_t)src | ((uint32_t)type << 19) |
                     ((uint32_t)(dst & 127) << 20);
    int cap = famA ? SCAPA : SCAPB;
    int* cnt = famA ? cnt_a : cnt_b;
    uint32_t* buck = famA ? buck_a : buck_b;
    int slot = atomicAdd(&cnt[xcd * NBUCK + bucket], 1);
    if (slot < cap) {
        atomicExch(&buck[((size_t)bucket * 8 + xcd) * cap + slot], entry);
    } else {
        bool placed = false;
        for (int d = 1; d < 8; ++d) {
            int s2 = (xcd + d) & 7;
            int sl2 = atomicAdd(&cnt[s2 * NBUCK + bucket], 1);
            if (sl2 < cap) {
                atomicExch(&buck[((size_t)bucket * 8 + s2) * cap + sl2], entry);
                placed = true;
                break;
            }
        }
        if (!placed) {
            int o = atomicAdd(ocnt, 1);
            if (o < OCAP)
                oflow[o] = make_uint2((uint32_t)dst | ((uint32_t)famA << 30) |
                                      ((uint32_t)type << 29), (uint32_t)src);
        }
    }
}

// ---- K2: per-bucket counting sort in LDS + layer-1 scalar aggregation ----
__global__ __launch_bounds__(256) void sort_agg(
    const int* __restrict__ cnt_a, const int* __restrict__ cnt_b,
    uint32_t* __restrict__ buck_a, uint32_t* __restrict__ buck_b,
    const float* __restrict__ xa, const float* __restrict__ xb,
    float* __restrict__ agg_ba, float* __restrict__ agg_aa,
    float* __restrict__ agg_ab,
    uint16_t* __restrict__ start16_a, uint16_t* __restrict__ start16_b,
    uint16_t* __restrict__ ktot_a, uint16_t* __restrict__ ktot_b) {
    __shared__ uint32_t raw[8 * SCAPA];
    __shared__ uint32_t sorted[8 * SCAPA];
    __shared__ int hist[128], cursor[128], startS[128], fillC[128];
    __shared__ int offS[9];
    __shared__ float sAgg[256];
    const int bucket = blockIdx.x;
    const int isA = (blockIdx.y == 0);
    const int cap = isA ? SCAPA : SCAPB;
    const int* cnt = isA ? cnt_a : cnt_b;
    uint32_t* buckbase = (isA ? buck_a : buck_b) + (size_t)bucket * 8 * cap;
    const int t = threadIdx.x;
    if (t < 128) hist[t] = 0;
    sAgg[t] = 0.f;
    if (t == 0) {
        int acc = 0;
        offS[0] = 0;
        for (int s = 0; s < 8; ++s) {
            int c = cnt[s * NBUCK + bucket];
            c = c < cap ? c : cap;
            acc += c;
            offS[s + 1] = acc;
        }
    }
    __syncthreads();
    const int K = offS[8];
    for (int i = t; i < K; i += 256) {
        int s = 0;
        while (i >= offS[s + 1]) ++s;
        uint32_t e = buckbase[s * cap + (i - offS[s])];
        raw[i] = e;
        atomicAdd(&hist[e >> 20], 1);
    }
    __syncthreads();
    if (t < 128) cursor[t] = hist[t];
    __syncthreads();
    for (int off = 1; off < 128; off <<= 1) {
        int v = 0;
        if (t < 128) { v = cursor[t]; if (t >= off) v += cursor[t - off]; }
        __syncthreads();
        if (t < 128) cursor[t] = v;
        __syncthreads();
    }
    if (t < 128) {
        int st = cursor[t] - hist[t];
        startS[t] = st;
        fillC[t] = st;
    }
    __syncthreads();
    for (int i = t; i < K; i += 256) {
        uint32_t e = raw[i];
        int loc = e >> 20;
        int type = (e >> 19) & 1;
        int src = e & 0x7FFFF;
        int pos = atomicAdd(&fillC[loc], 1);
        sorted[pos] = e;
        float xv = isA ? (type ? xa[src] : xb[src]) : xa[src];
        atomicAdd(&sAgg[loc * 2 + type], xv);
    }
    __syncthreads();
    for (int i = t; i < K; i += 256) buckbase[i] = sorted[i];
    if (t == 0) {
        if (isA) ktot_a[bucket] = (uint16_t)K;
        else     ktot_b[bucket] = (uint16_t)K;
    }
    if (t < 128) {
        int n = bucket * 128 + t;
        if (isA) {
            start16_a[bucket * 128 + t] = (uint16_t)startS[t];
            if (n < NA) {
                agg_ba[n] = sAgg[t * 2];
                agg_aa[n] = sAgg[t * 2 + 1];
            }
        } else {
            start16_b[bucket * 128 + t] = (uint16_t)startS[t];
            if (n < NB) agg_ab[n] = sAgg[t * 2];
        }
    }
}

// ---- K2b: overflow agg fixup (normally ~zero iterations) ----
__global__ __launch_bounds__(256) void oflow_agg(
    const int* __restrict__ ocnt, const uint2* __restrict__ oflow,
    const float* __restrict__ xa, const float* __restrict__ xb,
    float* __restrict__ agg_ba, float* __restrict__ agg_aa,
    float* __restrict__ agg_ab) {
    int n = *ocnt;
    n = n < OCAP ? n : OCAP;
    for (int i = threadIdx.x; i < n; i += 256) {
        uint2 r = oflow[i];
        int dst = r.x & 0x1FFFFFFF;
        int famA = (r.x >> 30) & 1;
        int type = (r.x >> 29) & 1;
        int src = (int)r.y;
        if (famA) {
            if (type) atomicAdd(&agg_aa[dst], xa[src]);
            else      atomicAdd(&agg_ba[dst], xb[src]);
        } else {
            atomicAdd(&agg_ab[dst], xa[src]);
        }
    }
}

// ---- K5: overflow out fixup (after gather; normally ~zero iterations) ----
__global__ __launch_bounds__(256) void oflow_out(
    const int* __restrict__ ocnt, const uint2* __restrict__ oflow,
    const uint16_t* __restrict__ ta0, const uint16_t* __restrict__ ta2,
    const uint16_t* __restrict__ tb1,
    float* __restrict__ outa, float* __restrict__ outb) {
    int n = *ocnt;
    n = n < OCAP ? n : OCAP;
    for (int i = threadIdx.x; i < n; i += 256) {
        uint2 r = oflow[i];
        int dst = r.x & 0x1FFFFFFF;
        int famA = (r.x >> 30) & 1;
        int type = (r.x >> 29) & 1;
        int src = (int)r.y;
        const uint16_t* tp = famA ? (type ? ta2 : tb1) : ta0;
        float* out = famA ? outa : outb;
        for (int k = 0; k < 32; ++k) {
            float v = __builtin_bit_cast(float,
                          (uint32_t)tp[(size_t)src * 32 + k] << 16);
            atomicAdd(&out[(size_t)dst * 32 + k], v);
        }
    }
}

// ---- K4: gather, 8 lanes per dst node ----
__global__ __launch_bounds__(256) void gather_out(
    const uint16_t* __restrict__ ktot_a, const uint16_t* __restrict__ ktot_b,
    const uint16_t* __restrict__ start16_a, const uint16_t* __restrict__ start16_b,
    const uint32_t* __restrict__ buck_a, const uint32_t* __restrict__ buck_b,
    const uint16_t* __restrict__ ta0, const uint16_t* __restrict__ ta2,
    const uint16_t* __restrict__ tb1,
    float* __restrict__ outa, float* __restrict__ outb) {
    int gid = blockIdx.x * 256 + threadIdx.x;   // exactly (NA+NB)*8 threads
    int n3 = gid >> 3;
    int l = gid & 7;
    float4 acc = make_float4(0.f, 0.f, 0.f, 0.f);
    if (n3 < NA) {
        int bucket = n3 >> 7, local = n3 & 127;
        int start = start16_a[n3];
        int end;
        if (local == 127) end = ktot_a[bucket];
        else              end = start16_a[n3 + 1];
        const uint32_t* bp = buck_a + (size_t)bucket * (8 * SCAPA);
        for (int i = start; i < end; ++i) {
            uint32_t e = bp[i];
            int src = e & 0x7FFFF;
            const uint16_t* tp = (e & (1u << 19)) ? ta2 : tb1;
            uint2 u = *(const uint2*)(tp + (size_t)src * 32 + l * 4);
            acc.x += __builtin_bit_cast(float, u.x << 16);
            acc.y += __builtin_bit_cast(float, u.x & 0xFFFF0000u);
            acc.z += __builtin_bit_cast(float, u.y << 16);
            acc.w += __builtin_bit_cast(float, u.y & 0xFFFF0000u);
        }
        float4* po = (float4*)(outa + (size_t)n3 * 32 + l * 4);
        float4 cur = *po;
        *po = make_float4(cur.x + acc.x, cur.y + acc.y, cur.z + acc.z, cur.w + acc.w);
    } else {
        int n = n3 - NA;
        int bucket = n >> 7, local = n & 127;
        int start = start16_b[n];
        int end;
        if (local == 127) end = ktot_b[bucket];
        else              end = start16_b[n + 1];
        const uint32_t* bp = buck_b + (size_t)bucket * (8 * SCAPB);
        for (int i = start; i < end; ++i) {
            uint32_t e = bp[i];
            int src = e & 0x7FFFF;
            uint2 u = *(const uint2*)(ta0 + (size_t)src * 32 + l * 4);
            acc.x += __builtin_bit_cast(float, u.x << 16);
            acc.y += __builtin_bit_cast(float, u.x & 0xFFFF0000u);
            acc.z += __builtin_bit_cast(float, u.y << 16);
            acc.w += __builtin_bit_cast(float, u.y & 0xFFFF0000u);
        }
        float4* po = (float4*)(outb + (size_t)n * 32 + l * 4);
        float4 cur = *po;
        *po = make_float4(cur.x + acc.x, cur.y + acc.y, cur.z + acc.z, cur.w + acc.w);
    }
}

// ---- prep_weights: uvwc/bias pack + MFMA B-fragment pack (hi/lo split) ----
// wpack floats: [2048:2304) uvwcA f4[64]; [2304:2560) uvwcB f4[64];
//               [2560:2592) bbA[32]; [2592:2624) bbB[32]
// wfrag: [mat(5)][tt(2)][s(2)][lane(64)][4 u32] = 5120 u32 per array.
//   B-frag: lane supplies W[k = s*32 + (lane>>4)*8 + i][col = tt*16 + (lane&15)]
//   mats: 0=Wrel2[0] 1=Wrel2[2] 2=Wroot2[1]+Wroot2[2] 3=Wrel2[1] 4=Wroot2[0]
__global__ __launch_bounds__(256) void prep_weights(
    const float* __restrict__ Wrel1, const float* __restrict__ Wroot1,
    const float* __restrict__ b1,
    const float* __restrict__ Wrel2, const float* __restrict__ Wroot2,
    const float* __restrict__ b2,
    float* __restrict__ wpack,
    uint32_t* __restrict__ whi, uint32_t* __restrict__ wlo) {
    const int t = threadIdx.x;
    if (t < 64) {
        float4* uvA = (float4*)(wpack + 2048);
        float4* uvB = (float4*)(wpack + 2304);
        uvA[t] = make_float4(Wrel1[64 + t], Wrel1[128 + t],
                             Wroot1[64 + t] + Wroot1[128 + t],
                             b1[64 + t] + b1[128 + t]);
        uvB[t] = make_float4(Wrel1[t], 0.f, Wroot1[t], b1[t]);
    }
    if (t >= 64 && t < 96) {
        int o = t - 64;
        wpack[2560 + o] = b2[32 + o] + b2[64 + o];
        wpack[2592 + o] = b2[o];
    }
    for (int w = t; w < 5120; w += 256) {   // 5 mats x 1024 u32
        int j = w & 3;
        int lane = (w >> 2) & 63;
        int s = (w >> 8) & 1;
        int tt = (w >> 9) & 1;
        int m = w >> 10;                    // 0..4
        int k0 = s * 32 + ((lane >> 4) << 3) + 2 * j;
        int col = tt * 16 + (lane & 15);
        int i0 = k0 * 32 + col, i1 = i0 + 32;
        float v0, v1;
        if (m == 0)      { v0 = Wrel2[i0];              v1 = Wrel2[i1]; }
        else if (m == 1) { v0 = Wrel2[4096 + i0];       v1 = Wrel2[4096 + i1]; }
        else if (m == 2) { v0 = Wroot2[2048 + i0] + Wroot2[4096 + i0];
                           v1 = Wroot2[2048 + i1] + Wroot2[4096 + i1]; }
        else if (m == 3) { v0 = Wrel2[2048 + i0];       v1 = Wrel2[2048 + i1]; }
        else             { v0 = Wroot2[i0];             v1 = Wroot2[i1]; }
        uint32_t h0 = f2bf(v0), h1 = f2bf(v1);
        float r0 = v0 - bf2f(h0);
        float r1 = v1 - bf2f(h1);
        whi[w] = h0 | (h1 << 16);
        wlo[w] = f2bf(r0) | (f2bf(r1) << 16);
    }
}

// 3-product split-bf16 pass over one matrix: acc = h_hi*W_hi + h_lo*W_hi
// + h_hi*W_lo (lo*lo term ~2^-18, dropped). Accuracy ~fp32.
#define NODE_PASS(MAT, INIT0, INIT1, A0, A1)                                 \
    f32x4 A0 = {(INIT0), (INIT0), (INIT0), (INIT0)};                         \
    f32x4 A1 = {(INIT1), (INIT1), (INIT1), (INIT1)};                         \
    {                                                                        \
        _Pragma("unroll")                                                    \
        for (int s = 0; s < 2; ++s) {                                        \
            bf16x8 bh0 = __builtin_bit_cast(bf16x8, fhi[((MAT)*4 + s)*64 + lane]);     \
            bf16x8 bl0 = __builtin_bit_cast(bf16x8, flo[((MAT)*4 + s)*64 + lane]);     \
            bf16x8 bh1 = __builtin_bit_cast(bf16x8, fhi[((MAT)*4 + 2 + s)*64 + lane]); \
            bf16x8 bl1 = __builtin_bit_cast(bf16x8, flo[((MAT)*4 + 2 + s)*64 + lane]); \
            A0 = MFMA16(ahi[s], bh0, A0, 0, 0, 0);                           \
            A0 = MFMA16(alo[s], bh0, A0, 0, 0, 0);                           \
            A0 = MFMA16(ahi[s], bl0, A0, 0, 0, 0);                           \
            A1 = MFMA16(ahi[s], bh1, A1, 0, 0, 0);                           \
            A1 = MFMA16(alo[s], bh1, A1, 0, 0, 0);                           \
            A1 = MFMA16(ahi[s], bl1, A1, 0, 0, 0);                           \
        }                                                                    \
    }

// bf16 table epilogue: D layout col=lane&15, row=kg*4+r (m89-verified).
// Restage through wave-private LDS for coalesced 16B row stores.
#define STORE_TABLE(A0, A1, TP)                                              \
    {                                                                        \
        _Pragma("unroll")                                                    \
        for (int r = 0; r < 4; ++r) {                                        \
            st[wid][kg * 4 + r][mrow]      = (uint16_t)f2bf(A0[r]);          \
            st[wid][kg * 4 + r][16 + mrow] = (uint16_t)f2bf(A1[r]);          \
        }                                                                    \
        int r2 = lane >> 2, cq = lane & 3;                                   \
        int nd = nbase + wid * 16 + r2;                                      \
        if (nd < NA) {                                                       \
            uint4 v = *(const uint4*)&st[wid][r2][cq * 8];                   \
            *((uint4*)((TP) + (size_t)nd * 32) + cq) = v;                    \
        }                                                                    \
    }

// f32 output epilogue: direct stores (4-node 64B segments per inst).
#define STORE_OUT(A0, A1, OP)                                                \
    {                                                                        \
        _Pragma("unroll")                                                    \
        for (int r = 0; r < 4; ++r) {                                        \
            int nd = nbase + wid * 16 + kg * 4 + r;                          \
            if (nd < NA) {                                                   \
                (OP)[(size_t)nd * 32 + mrow]      = A0[r];                   \
                (OP)[(size_t)nd * 32 + 16 + mrow] = A1[r];                   \
            }                                                                \
        }                                                                    \
    }

// ============ MFMA node kernel: even blocks = A-family, odd = B ============
// Wave = 16 nodes; block = 64 nodes. A: h once -> {ta0, ta2, outa};
// B: h once -> {tb1, outb}. h built per-lane directly in A-frag layout
// (row = lane&15, k = (lane>>4)*8 + i), split hi/lo bf16.
__global__ __launch_bounds__(256) void node_mfma(
    const float* __restrict__ xa, const float* __restrict__ xb,
    const float* __restrict__ s_ba, const float* __restrict__ s_aa,
    const float* __restrict__ s_ab,
    const float* __restrict__ wpack,
    const uint4* __restrict__ fhi, const uint4* __restrict__ flo,
    uint16_t* __restrict__ ta0, uint16_t* __restrict__ ta2,
    uint16_t* __restrict__ tb1,
    float* __restrict__ outa, float* __restrict__ outb) {
    __shared__ float4 uvS[64];
    __shared__ uint16_t st[4][16][32];
    const int tid = threadIdx.x;
    const bool isA = (blockIdx.x & 1) == 0;
    const int nbase = (blockIdx.x >> 1) * 64;
    const int wid = tid >> 6, lane = tid & 63;
    const int mrow = lane & 15, kg = lane >> 4;

    if (tid < 64) uvS[tid] = ((const float4*)(wpack + (isA ? 2048 : 2304)))[tid];
    __syncthreads();

    const int node = nbase + wid * 16 + mrow;
    const bool vin = node < NA;            // NA == NB
    float i0 = 0.f, i1 = 0.f, i2 = 0.f;
    if (isA) {
        if (vin) { i0 = s_ba[node]; i1 = s_aa[node]; i2 = xa[node]; }
    } else {
        if (vin) { i0 = s_ab[node]; i2 = xb[node]; }
    }
    const float bb0 = wpack[(isA ? 2560 : 2592) + mrow];
    const float bb1 = wpack[(isA ? 2560 : 2592) + 16 + mrow];

    // A fragments (h), split hi/lo
    bf16x8 ahi[2], alo[2];
#pragma unroll
    for (int s = 0; s < 2; ++s) {
#pragma unroll
        for (int i = 0; i < 8; ++i) {
            int k = s * 32 + kg * 8 + i;
            float4 c4 = uvS[k];
            float hv = fmaxf(fmaf(i0, c4.x, fmaf(i1, c4.y, fmaf(i2, c4.z, c4.w))), 0.f);
            uint32_t hb = f2bf(hv);
            float rv = hv - bf2f(hb);
            ahi[s][i] = (short)hb;
            alo[s][i] = (short)f2bf(rv);
        }
    }

    if (isA) {
        { NODE_PASS(0, 0.f, 0.f, p0, p1) STORE_TABLE(p0, p1, ta0) }
        { NODE_PASS(1, 0.f, 0.f, q0, q1) STORE_TABLE(q0, q1, ta2) }
        { NODE_PASS(2, bb0, bb1, r0v, r1v) STORE_OUT(r0v, r1v, outa) }
    } else {
        { NODE_PASS(3, 0.f, 0.f, p0, p1) STORE_TABLE(p0, p1, tb1) }
        { NODE_PASS(4, bb0, bb1, r0v, r1v) STORE_OUT(r0v, r1v, outb) }
    }
}

extern "C" void kernel_launch(void* const* d_in, const int* in_sizes, int n_in,
                              void* d_out, int out_size, void* d_ws, size_t ws_size,
                              hipStream_t stream) {
    const float* x_a    = (const float*)d_in[0];
    const float* x_b    = (const float*)d_in[1];
    const int*   ei_ab  = (const int*)d_in[2];
    const int*   ei_ba  = (const int*)d_in[3];
    const int*   ei_aa  = (const int*)d_in[4];
    const float* Wrel1  = (const float*)d_in[5];
    const float* Wroot1 = (const float*)d_in[6];
    const float* b1     = (const float*)d_in[7];
    const float* Wrel2  = (const float*)d_in[8];
    const float* Wroot2 = (const float*)d_in[9];
    const float* b2     = (const float*)d_in[10];

    float* outa = (float*)d_out;                       // [NA,32]
    float* outb = (float*)d_out + (size_t)NA * 32;     // [NB,32]

    char* ws = (char*)d_ws;
    // Layout (bytes):
    uint32_t* buck_a   = (uint32_t*)(ws);                    // 3907*704*4  = 11,002,112
    uint32_t* buck_b   = (uint32_t*)(ws + 11002112);         // 3907*400*4  =  6,251,200
    float*    agg_ba   = (float*)(ws + 17253312);            // NA floats
    float*    agg_aa   = (float*)(ws + 19253312);            // NA floats
    float*    agg_ab   = (float*)(ws + 21253312);            // NB floats
    uint16_t* ta0      = (uint16_t*)(ws + 23253312);         // NA*32 bf16
    uint16_t* ta2      = (uint16_t*)(ws + 55253312);         // NA*32 bf16
    uint16_t* tb1      = (uint16_t*)(ws + 87253312);         // NB*32 bf16
    uint16_t* start16_a= (uint16_t*)(ws + 119253312);        // 3907*128 u16
    uint16_t* start16_b= (uint16_t*)(ws + 120253504);        // 3907*128 u16
    uint16_t* ktot_a   = (uint16_t*)(ws + 121253696);        // 3907 u16 (pad 8192)
    uint16_t* ktot_b   = (uint16_t*)(ws + 121261888);        // 3907 u16 (pad 8192)
    int*      cnt_a    = (int*)(ws + 121270080);             // 8*3907 int = 125,024
    int*      cnt_b    = (int*)(ws + 121395104);             // 8*3907 int
    int*      ocnt     = (int*)(ws + 121520128);             // 1 int (+4 pad)
    uint2*    oflow    = (uint2*)(ws + 121520136);           // 2048 uint2 = 16,384
    float*    wpack    = (float*)(ws + 121536576);           // 2624 floats = 10,496
    uint32_t* wfrag_hi = (uint32_t*)(ws + 121547072);        // 5120 u32 = 20,480
    uint32_t* wfrag_lo = (uint32_t*)(ws + 121567552);        // 5120 u32, ends 121,588,032
    if (ws_size < 121600000) return;  // need ~121.6 MB scratch

    // zero cnt_a, cnt_b, ocnt (one contiguous span)
    hipMemsetAsync((char*)cnt_a, 0, 125024 + 125024 + 8, stream);

    dim3 blk(256);
    prep_weights<<<1, blk, 0, stream>>>(Wrel1, Wroot1, b1, Wrel2, Wroot2, b2,
                                        wpack, wfrag_hi, wfrag_lo);

    int egrid = (3 * EE + 255) / 256;
    bucket_scatter<<<egrid, blk, 0, stream>>>(ei_ab, ei_ba, ei_aa, cnt_a, cnt_b,
                                              buck_a, buck_b, ocnt, oflow);

    sort_agg<<<dim3(NBUCK, 2), blk, 0, stream>>>(cnt_a, cnt_b, buck_a, buck_b,
                                                 x_a, x_b, agg_ba, agg_aa, agg_ab,
                                                 start16_a, start16_b,
                                                 ktot_a, ktot_b);
    oflow_agg<<<1, blk, 0, stream>>>(ocnt, oflow, x_a, x_b, agg_ba, agg_aa, agg_ab);

    int ngrid = ((NA + 63) / 64) * 2;   // 15626, even = A, odd = B
    node_mfma<<<ngrid, blk, 0, stream>>>(
        x_a, x_b, agg_ba, agg_aa, agg_ab, wpack,
        (const uint4*)wfrag_hi, (const uint4*)wfrag_lo,
        ta0, ta2, tb1, outa, outb);

    int ggrid = (int)(((size_t)(NA + NB) * 8) / 256);  // 31250 exact
    gather_out<<<ggrid, blk, 0, stream>>>(ktot_a, ktot_b, start16_a, start16_b,
                                          buck_a, buck_b, ta0, ta2, tb1,
                                          outa, outb);
    oflow_out<<<1, blk, 0, stream>>>(ocnt, oflow, ta0, ta2, tb1, outa, outb);
}

// Round 11
// 427.781 us; speedup vs baseline: 1.3946x; 1.3946x over previous
//
#include <hip/hip_runtime.h>
#include <hip/hip_bf16.h>
#include <stdint.h>

#define NA 500000
#define NB 500000
#define EE 1000000
#define NPART 245           // partitions per family: ceil(500000/2048)
#define CAPPA 8704          // famA partition cap: mean 8192 + ~5.7 sigma
#define CAPPB 4480          // famB partition cap: mean 4096 + ~6 sigma
#define TILE 8192           // edges per bin_edges block
#define OCAP 2048

typedef __attribute__((ext_vector_type(8))) short bf16x8;
typedef __attribute__((ext_vector_type(4))) float f32x4;
#define MFMA16 __builtin_amdgcn_mfma_f32_16x16x32_bf16

__device__ __forceinline__ uint32_t f2bf(float f) {
    uint32_t b = __builtin_bit_cast(uint32_t, f);
    return (b + 0x7FFFu + ((b >> 16) & 1u)) >> 16;  // RNE
}
__device__ __forceinline__ float bf2f(uint32_t h) {
    return __builtin_bit_cast(float, h << 16);
}

// ---- K1: coarse-bin edges into 490 partitions (fam x dst>>11) ----
// All scattered traffic is staged in LDS; global writes are partition-ordered
// runs (avg ~67B) flushed by consecutive lanes -> near-full-line transactions.
// (R9/R10 evidence: scattered dword stores AND atomics cost ~32B/op at memory
// regardless of locality -> only coalesced wave stores avoid amplification.)
__global__ __launch_bounds__(256) void bin_edges(
    const int* __restrict__ ei_ab, const int* __restrict__ ei_ba,
    const int* __restrict__ ei_aa,
    int* __restrict__ pcnt,
    uint32_t* __restrict__ buck_a, uint32_t* __restrict__ buck_b,
    int* __restrict__ ocnt, uint2* __restrict__ oflow) {
    __shared__ int hist[512], start[512], base_[512], cursor[512];
    __shared__ int tsum[256];
    __shared__ uint32_t sbuf[TILE];
    __shared__ uint16_t pid[TILE];
    const int t = threadIdx.x;
    const int tile0 = blockIdx.x * TILE;
    int tcount = 3 * EE - tile0;
    tcount = tcount < 0 ? 0 : (tcount > TILE ? TILE : tcount);

    for (int i = t; i < 512; i += 256) hist[i] = 0;
    __syncthreads();

    // pass A: histogram over partitions
    for (int it = 0; it < TILE / 256; ++it) {
        int gid = tile0 + it * 256 + t;
        if (gid < 3 * EE) {
            int dst, famA;
            if (gid < EE)          { dst = ei_ab[EE + gid]; famA = 0; }
            else if (gid < 2 * EE) { int e = gid - EE;     dst = ei_ba[EE + e]; famA = 1; }
            else                   { int e = gid - 2 * EE; dst = ei_aa[EE + e]; famA = 1; }
            int p = (famA ? 0 : NPART) + (dst >> 11);
            atomicAdd(&hist[p], 1);
        }
    }
    __syncthreads();
    // exclusive scan of hist[512]: 2 bins/thread + 256-wide scan
    int a = hist[2 * t], b = hist[2 * t + 1];
    tsum[t] = a + b;
    __syncthreads();
    for (int off = 1; off < 256; off <<= 1) {
        int v = tsum[t];
        if (t >= off) v += tsum[t - off];
        __syncthreads();
        tsum[t] = v;
        __syncthreads();
    }
    int ex = tsum[t] - (a + b);
    start[2 * t] = ex;          cursor[2 * t] = ex;
    start[2 * t + 1] = ex + a;  cursor[2 * t + 1] = ex + a;
    __syncthreads();
    // reserve global space per touched partition (1 atomic per part per tile)
    for (int p = t; p < 2 * NPART; p += 256) {
        int h = hist[p];
        if (h > 0) base_[p] = atomicAdd(&pcnt[p], h);
    }
    __syncthreads();
    // pass B: re-read edges (L2/L3 warm), place partition-ordered in LDS
    for (int it = 0; it < TILE / 256; ++it) {
        int gid = tile0 + it * 256 + t;
        if (gid < 3 * EE) {
            int dst, src, type, famA;
            if (gid < EE)          { dst = ei_ab[EE + gid]; src = ei_ab[gid]; type = 0; famA = 0; }
            else if (gid < 2 * EE) { int e = gid - EE;     dst = ei_ba[EE + e]; src = ei_ba[e]; type = 0; famA = 1; }
            else                   { int e = gid - 2 * EE; dst = ei_aa[EE + e]; src = ei_aa[e]; type = 1; famA = 1; }
            int p = (famA ? 0 : NPART) + (dst >> 11);
            uint32_t entry = (uint32_t)src | ((uint32_t)type << 19) |
                             ((uint32_t)(dst & 2047) << 20);
            int pos = atomicAdd(&cursor[p], 1);
            sbuf[pos] = entry;
            pid[pos] = (uint16_t)p;
        }
    }
    __syncthreads();
    // flush: consecutive lanes -> consecutive addresses within each run
    for (int i = t; i < tcount; i += 256) {
        int p = pid[i];
        uint32_t e = sbuf[i];
        int rel = base_[p] + (i - start[p]);
        bool isA = p < NPART;
        int cap = isA ? CAPPA : CAPPB;
        if (rel < cap) {
            if (isA) buck_a[(size_t)p * CAPPA + rel] = e;
            else     buck_b[(size_t)(p - NPART) * CAPPB + rel] = e;
        } else {
            int local = (e >> 20) & 2047;
            int dst = ((isA ? p : p - NPART) << 11) + local;
            int type = (e >> 19) & 1;
            int src = e & 0x7FFFF;
            int o = atomicAdd(ocnt, 1);
            if (o < OCAP)
                oflow[o] = make_uint2((uint32_t)dst | ((uint32_t)(isA ? 1 : 0) << 30) |
                                      ((uint32_t)type << 29), (uint32_t)src);
        }
    }
}

// ---- K2: per-partition counting sort (2048 dst-locals) + layer-1 aggs ----
// Reads region twice (hist, place), writes sorted back coalesced.
__global__ __launch_bounds__(256) void part_sort_agg(
    const int* __restrict__ pcnt,
    uint32_t* __restrict__ buck_a, uint32_t* __restrict__ buck_b,
    const float* __restrict__ xa, const float* __restrict__ xb,
    float* __restrict__ agg_ba, float* __restrict__ agg_aa,
    float* __restrict__ agg_ab,
    uint16_t* __restrict__ start16_a, uint16_t* __restrict__ start16_b,
    uint16_t* __restrict__ ktot_a, uint16_t* __restrict__ ktot_b) {
    __shared__ uint32_t sorted[CAPPA];
    __shared__ int hist[2048], fill[2048];
    __shared__ int tsum[256];
    const int part = blockIdx.x;
    const int isA = (blockIdx.y == 0);
    const int p = isA ? part : NPART + part;
    const int cap = isA ? CAPPA : CAPPB;
    uint32_t* region = isA ? (buck_a + (size_t)part * CAPPA)
                           : (buck_b + (size_t)part * CAPPB);
    const int t = threadIdx.x;
    int K = pcnt[p];
    K = K < cap ? K : cap;

    for (int i = t; i < 2048; i += 256) hist[i] = 0;
    __syncthreads();
    for (int i = t; i < K; i += 256)
        atomicAdd(&hist[(region[i] >> 20) & 2047], 1);
    __syncthreads();
    // exclusive scan of hist[2048]: 8 bins/thread serial + 256-wide scan
    int base8 = t * 8;
    int s0 = 0, loc[8];
#pragma unroll
    for (int j = 0; j < 8; ++j) { loc[j] = s0; s0 += hist[base8 + j]; }
    tsum[t] = s0;
    __syncthreads();
    for (int off = 1; off < 256; off <<= 1) {
        int v = tsum[t];
        if (t >= off) v += tsum[t - off];
        __syncthreads();
        tsum[t] = v;
        __syncthreads();
    }
    int ex = tsum[t] - s0;
#pragma unroll
    for (int j = 0; j < 8; ++j) fill[base8 + j] = ex + loc[j];
    __syncthreads();
    // start16 (partition-relative, K<=8704 fits u16) + ktot
    {
        uint16_t* s16 = isA ? start16_a : start16_b;
        for (int d = t; d < 2048; d += 256)
            s16[part * 2048 + d] = (uint16_t)fill[d];
        if (t == 0) {
            if (isA) ktot_a[part] = (uint16_t)K;
            else     ktot_b[part] = (uint16_t)K;
        }
    }
    __syncthreads();
    // place
    for (int i = t; i < K; i += 256) {
        uint32_t e = region[i];
        int pos = atomicAdd(&fill[(e >> 20) & 2047], 1);
        sorted[pos] = e;
    }
    __syncthreads();
    // write back coalesced
    for (int i = t; i < K; i += 256) region[i] = sorted[i];
    // layer-1 aggregates from sorted runs (fill[d]=end, hist[d]=count)
    for (int d = t; d < 2048; d += 256) {
        int n = part * 2048 + d;
        if (n >= NA) continue;              // NA == NB
        int end = fill[d], st = end - hist[d];
        if (isA) {
            float sba = 0.f, saa = 0.f;
            for (int i = st; i < end; ++i) {
                uint32_t e = sorted[i];
                int src = e & 0x7FFFF;
                if ((e >> 19) & 1) saa += xa[src];
                else               sba += xb[src];
            }
            agg_ba[n] = sba;
            agg_aa[n] = saa;
        } else {
            float sab = 0.f;
            for (int i = st; i < end; ++i) sab += xa[sorted[i] & 0x7FFFF];
            agg_ab[n] = sab;
        }
    }
}

// ---- K2b: overflow agg fixup (normally ~zero iterations) ----
__global__ __launch_bounds__(256) void oflow_agg(
    const int* __restrict__ ocnt, const uint2* __restrict__ oflow,
    const float* __restrict__ xa, const float* __restrict__ xb,
    float* __restrict__ agg_ba, float* __restrict__ agg_aa,
    float* __restrict__ agg_ab) {
    int n = *ocnt;
    n = n < OCAP ? n : OCAP;
    for (int i = threadIdx.x; i < n; i += 256) {
        uint2 r = oflow[i];
        int dst = r.x & 0x1FFFFFFF;
        int famA = (r.x >> 30) & 1;
        int type = (r.x >> 29) & 1;
        int src = (int)r.y;
        if (famA) {
            if (type) atomicAdd(&agg_aa[dst], xa[src]);
            else      atomicAdd(&agg_ba[dst], xb[src]);
        } else {
            atomicAdd(&agg_ab[dst], xa[src]);
        }
    }
}

// ---- K5: overflow out fixup (after gather; normally ~zero iterations) ----
__global__ __launch_bounds__(256) void oflow_out(
    const int* __restrict__ ocnt, const uint2* __restrict__ oflow,
    const uint16_t* __restrict__ ta0, const uint16_t* __restrict__ ta2,
    const uint16_t* __restrict__ tb1,
    float* __restrict__ outa, float* __restrict__ outb) {
    int n = *ocnt;
    n = n < OCAP ? n : OCAP;
    for (int i = threadIdx.x; i < n; i += 256) {
        uint2 r = oflow[i];
        int dst = r.x & 0x1FFFFFFF;
        int famA = (r.x >> 30) & 1;
        int type = (r.x >> 29) & 1;
        int src = (int)r.y;
        const uint16_t* tp = famA ? (type ? ta2 : tb1) : ta0;
        float* out = famA ? outa : outb;
        for (int k = 0; k < 32; ++k) {
            float v = __builtin_bit_cast(float,
                          (uint32_t)tp[(size_t)src * 32 + k] << 16);
            atomicAdd(&out[(size_t)dst * 32 + k], v);
        }
    }
}

// ---- K4: gather, 8 lanes per dst node (partition geometry) ----
__global__ __launch_bounds__(256) void gather_out(
    const uint16_t* __restrict__ ktot_a, const uint16_t* __restrict__ ktot_b,
    const uint16_t* __restrict__ start16_a, const uint16_t* __restrict__ start16_b,
    const uint32_t* __restrict__ buck_a, const uint32_t* __restrict__ buck_b,
    const uint16_t* __restrict__ ta0, const uint16_t* __restrict__ ta2,
    const uint16_t* __restrict__ tb1,
    float* __restrict__ outa, float* __restrict__ outb) {
    int gid = blockIdx.x * 256 + threadIdx.x;   // exactly (NA+NB)*8 threads
    int n3 = gid >> 3;
    int l = gid & 7;
    float4 acc = make_float4(0.f, 0.f, 0.f, 0.f);
    if (n3 < NA) {
        int part = n3 >> 11, local = n3 & 2047;
        int start = start16_a[n3];
        int end = (local == 2047) ? (int)ktot_a[part] : (int)start16_a[n3 + 1];
        const uint32_t* bp = buck_a + (size_t)part * CAPPA;
        for (int i = start; i < end; ++i) {
            uint32_t e = bp[i];
            int src = e & 0x7FFFF;
            const uint16_t* tp = (e & (1u << 19)) ? ta2 : tb1;
            uint2 u = *(const uint2*)(tp + (size_t)src * 32 + l * 4);
            acc.x += __builtin_bit_cast(float, u.x << 16);
            acc.y += __builtin_bit_cast(float, u.x & 0xFFFF0000u);
            acc.z += __builtin_bit_cast(float, u.y << 16);
            acc.w += __builtin_bit_cast(float, u.y & 0xFFFF0000u);
        }
        float4* po = (float4*)(outa + (size_t)n3 * 32 + l * 4);
        float4 cur = *po;
        *po = make_float4(cur.x + acc.x, cur.y + acc.y, cur.z + acc.z, cur.w + acc.w);
    } else {
        int n = n3 - NA;
        int part = n >> 11, local = n & 2047;
        int start = start16_b[n];
        int end = (local == 2047) ? (int)ktot_b[part] : (int)start16_b[n + 1];
        const uint32_t* bp = buck_b + (size_t)part * CAPPB;
        for (int i = start; i < end; ++i) {
            uint32_t e = bp[i];
            int src = e & 0x7FFFF;
            uint2 u = *(const uint2*)(ta0 + (size_t)src * 32 + l * 4);
            acc.x += __builtin_bit_cast(float, u.x << 16);
            acc.y += __builtin_bit_cast(float, u.x & 0xFFFF0000u);
            acc.z += __builtin_bit_cast(float, u.y << 16);
            acc.w += __builtin_bit_cast(float, u.y & 0xFFFF0000u);
        }
        float4* po = (float4*)(outb + (size_t)n * 32 + l * 4);
        float4 cur = *po;
        *po = make_float4(cur.x + acc.x, cur.y + acc.y, cur.z + acc.z, cur.w + acc.w);
    }
}

// ---- prep_weights: uvwc/bias pack + MFMA B-fragment pack (hi/lo split) ----
// wpack floats: [2048:2304) uvwcA f4[64]; [2304:2560) uvwcB f4[64];
//               [2560:2592) bbA[32]; [2592:2624) bbB[32]
// wfrag: [mat(5)][tt(2)][s(2)][lane(64)][4 u32] = 5120 u32 per array.
//   B-frag: lane supplies W[k = s*32 + (lane>>4)*8 + i][col = tt*16 + (lane&15)]
//   mats: 0=Wrel2[0] 1=Wrel2[2] 2=Wroot2[1]+Wroot2[2] 3=Wrel2[1] 4=Wroot2[0]
__global__ __launch_bounds__(256) void prep_weights(
    const float* __restrict__ Wrel1, const float* __restrict__ Wroot1,
    const float* __restrict__ b1,
    const float* __restrict__ Wrel2, const float* __restrict__ Wroot2,
    const float* __restrict__ b2,
    float* __restrict__ wpack,
    uint32_t* __restrict__ whi, uint32_t* __restrict__ wlo) {
    const int t = threadIdx.x;
    if (t < 64) {
        float4* uvA = (float4*)(wpack + 2048);
        float4* uvB = (float4*)(wpack + 2304);
        uvA[t] = make_float4(Wrel1[64 + t], Wrel1[128 + t],
                             Wroot1[64 + t] + Wroot1[128 + t],
                             b1[64 + t] + b1[128 + t]);
        uvB[t] = make_float4(Wrel1[t], 0.f, Wroot1[t], b1[t]);
    }
    if (t >= 64 && t < 96) {
        int o = t - 64;
        wpack[2560 + o] = b2[32 + o] + b2[64 + o];
        wpack[2592 + o] = b2[o];
    }
    for (int w = t; w < 5120; w += 256) {   // 5 mats x 1024 u32
        int j = w & 3;
        int lane = (w >> 2) & 63;
        int s = (w >> 8) & 1;
        int tt = (w >> 9) & 1;
        int m = w >> 10;                    // 0..4
        int k0 = s * 32 + ((lane >> 4) << 3) + 2 * j;
        int col = tt * 16 + (lane & 15);
        int i0 = k0 * 32 + col, i1 = i0 + 32;
        float v0, v1;
        if (m == 0)      { v0 = Wrel2[i0];              v1 = Wrel2[i1]; }
        else if (m == 1) { v0 = Wrel2[4096 + i0];       v1 = Wrel2[4096 + i1]; }
        else if (m == 2) { v0 = Wroot2[2048 + i0] + Wroot2[4096 + i0];
                           v1 = Wroot2[2048 + i1] + Wroot2[4096 + i1]; }
        else if (m == 3) { v0 = Wrel2[2048 + i0];       v1 = Wrel2[2048 + i1]; }
        else             { v0 = Wroot2[i0];             v1 = Wroot2[i1]; }
        uint32_t h0 = f2bf(v0), h1 = f2bf(v1);
        float r0 = v0 - bf2f(h0);
        float r1 = v1 - bf2f(h1);
        whi[w] = h0 | (h1 << 16);
        wlo[w] = f2bf(r0) | (f2bf(r1) << 16);
    }
}

// 3-product split-bf16 pass over one matrix: acc = h_hi*W_hi + h_lo*W_hi
// + h_hi*W_lo (lo*lo term ~2^-18, dropped). Accuracy ~fp32.
#define NODE_PASS(MAT, INIT0, INIT1, A0, A1)                                 \
    f32x4 A0 = {(INIT0), (INIT0), (INIT0), (INIT0)};                         \
    f32x4 A1 = {(INIT1), (INIT1), (INIT1), (INIT1)};                         \
    {                                                                        \
        _Pragma("unroll")                                                    \
        for (int s = 0; s < 2; ++s) {                                        \
            bf16x8 bh0 = __builtin_bit_cast(bf16x8, fhi[((MAT)*4 + s)*64 + lane]);     \
            bf16x8 bl0 = __builtin_bit_cast(bf16x8, flo[((MAT)*4 + s)*64 + lane]);     \
            bf16x8 bh1 = __builtin_bit_cast(bf16x8, fhi[((MAT)*4 + 2 + s)*64 + lane]); \
            bf16x8 bl1 = __builtin_bit_cast(bf16x8, flo[((MAT)*4 + 2 + s)*64 + lane]); \
            A0 = MFMA16(ahi[s], bh0, A0, 0, 0, 0);                           \
            A0 = MFMA16(alo[s], bh0, A0, 0, 0, 0);                           \
            A0 = MFMA16(ahi[s], bl0, A0, 0, 0, 0);                           \
            A1 = MFMA16(ahi[s], bh1, A1, 0, 0, 0);                           \
            A1 = MFMA16(alo[s], bh1, A1, 0, 0, 0);                           \
            A1 = MFMA16(ahi[s], bl1, A1, 0, 0, 0);                           \
        }                                                                    \
    }

// bf16 table epilogue: D layout col=lane&15, row=kg*4+r (m89-verified).
#define STORE_TABLE(A0, A1, TP)                                              \
    {                                                                        \
        _Pragma("unroll")                                                    \
        for (int r = 0; r < 4; ++r) {                                        \
            st[wid][kg * 4 + r][mrow]      = (uint16_t)f2bf(A0[r]);          \
            st[wid][kg * 4 + r][16 + mrow] = (uint16_t)f2bf(A1[r]);          \
        }                                                                    \
        int r2 = lane >> 2, cq = lane & 3;                                   \
        int nd = nbase + wid * 16 + r2;                                      \
        if (nd < NA) {                                                       \
            uint4 v = *(const uint4*)&st[wid][r2][cq * 8];                   \
            *((uint4*)((TP) + (size_t)nd * 32) + cq) = v;                    \
        }                                                                    \
    }

// f32 output epilogue: direct stores (4-node 64B segments per inst).
#define STORE_OUT(A0, A1, OP)                                                \
    {                                                                        \
        _Pragma("unroll")                                                    \
        for (int r = 0; r < 4; ++r) {                                        \
            int nd = nbase + wid * 16 + kg * 4 + r;                          \
            if (nd < NA) {                                                   \
                (OP)[(size_t)nd * 32 + mrow]      = A0[r];                   \
                (OP)[(size_t)nd * 32 + 16 + mrow] = A1[r];                   \
            }                                                                \
        }                                                                    \
    }

// ============ MFMA node kernel: even blocks = A-family, odd = B ============
__global__ __launch_bounds__(256) void node_mfma(
    const float* __restrict__ xa, const float* __restrict__ xb,
    const float* __restrict__ s_ba, const float* __restrict__ s_aa,
    const float* __restrict__ s_ab,
    const float* __restrict__ wpack,
    const uint4* __restrict__ fhi, const uint4* __restrict__ flo,
    uint16_t* __restrict__ ta0, uint16_t* __restrict__ ta2,
    uint16_t* __restrict__ tb1,
    float* __restrict__ outa, float* __restrict__ outb) {
    __shared__ float4 uvS[64];
    __shared__ uint16_t st[4][16][32];
    const int tid = threadIdx.x;
    const bool isA = (blockIdx.x & 1) == 0;
    const int nbase = (blockIdx.x >> 1) * 64;
    const int wid = tid >> 6, lane = tid & 63;
    const int mrow = lane & 15, kg = lane >> 4;

    if (tid < 64) uvS[tid] = ((const float4*)(wpack + (isA ? 2048 : 2304)))[tid];
    __syncthreads();

    const int node = nbase + wid * 16 + mrow;
    const bool vin = node < NA;            // NA == NB
    float i0 = 0.f, i1 = 0.f, i2 = 0.f;
    if (isA) {
        if (vin) { i0 = s_ba[node]; i1 = s_aa[node]; i2 = xa[node]; }
    } else {
        if (vin) { i0 = s_ab[node]; i2 = xb[node]; }
    }
    const float bb0 = wpack[(isA ? 2560 : 2592) + mrow];
    const float bb1 = wpack[(isA ? 2560 : 2592) + 16 + mrow];

    bf16x8 ahi[2], alo[2];
#pragma unroll
    for (int s = 0; s < 2; ++s) {
#pragma unroll
        for (int i = 0; i < 8; ++i) {
            int k = s * 32 + kg * 8 + i;
            float4 c4 = uvS[k];
            float hv = fmaxf(fmaf(i0, c4.x, fmaf(i1, c4.y, fmaf(i2, c4.z, c4.w))), 0.f);
            uint32_t hb = f2bf(hv);
            float rv = hv - bf2f(hb);
            ahi[s][i] = (short)hb;
            alo[s][i] = (short)f2bf(rv);
        }
    }

    if (isA) {
        { NODE_PASS(0, 0.f, 0.f, p0, p1) STORE_TABLE(p0, p1, ta0) }
        { NODE_PASS(1, 0.f, 0.f, q0, q1) STORE_TABLE(q0, q1, ta2) }
        { NODE_PASS(2, bb0, bb1, r0v, r1v) STORE_OUT(r0v, r1v, outa) }
    } else {
        { NODE_PASS(3, 0.f, 0.f, p0, p1) STORE_TABLE(p0, p1, tb1) }
        { NODE_PASS(4, bb0, bb1, r0v, r1v) STORE_OUT(r0v, r1v, outb) }
    }
}

extern "C" void kernel_launch(void* const* d_in, const int* in_sizes, int n_in,
                              void* d_out, int out_size, void* d_ws, size_t ws_size,
                              hipStream_t stream) {
    const float* x_a    = (const float*)d_in[0];
    const float* x_b    = (const float*)d_in[1];
    const int*   ei_ab  = (const int*)d_in[2];
    const int*   ei_ba  = (const int*)d_in[3];
    const int*   ei_aa  = (const int*)d_in[4];
    const float* Wrel1  = (const float*)d_in[5];
    const float* Wroot1 = (const float*)d_in[6];
    const float* b1     = (const float*)d_in[7];
    const float* Wrel2  = (const float*)d_in[8];
    const float* Wroot2 = (const float*)d_in[9];
    const float* b2     = (const float*)d_in[10];

    float* outa = (float*)d_out;                       // [NA,32]
    float* outb = (float*)d_out + (size_t)NA * 32;     // [NB,32]

    char* ws = (char*)d_ws;
    // Layout (bytes):
    uint32_t* buck_a   = (uint32_t*)(ws);                    // 245*8704*4 = 8,529,920
    uint32_t* buck_b   = (uint32_t*)(ws + 8529920);          // 245*4480*4 = 4,390,400
    float*    agg_ba   = (float*)(ws + 12920320);            // NA floats
    float*    agg_aa   = (float*)(ws + 14920320);            // NA floats
    float*    agg_ab   = (float*)(ws + 16920320);            // NB floats
    uint16_t* ta0      = (uint16_t*)(ws + 18920320);         // NA*32 bf16
    uint16_t* ta2      = (uint16_t*)(ws + 50920320);         // NA*32 bf16
    uint16_t* tb1      = (uint16_t*)(ws + 82920320);         // NB*32 bf16
    uint16_t* start16_a= (uint16_t*)(ws + 114920320);        // 245*2048 u16 = 1,003,520
    uint16_t* start16_b= (uint16_t*)(ws + 115923840);        // 245*2048 u16
    uint16_t* ktot_a   = (uint16_t*)(ws + 116927360);        // 245 u16 (pad 8192)
    uint16_t* ktot_b   = (uint16_t*)(ws + 116935552);        // 245 u16 (pad 8192)
    int*      pcnt     = (int*)(ws + 116943744);             // 512 int = 2,048
    int*      ocnt     = (int*)(ws + 116945792);             // 1 int (+4 pad)
    uint2*    oflow    = (uint2*)(ws + 116945800);           // 2048 uint2 = 16,384
    float*    wpack    = (float*)(ws + 116962192);           // 2624 floats = 10,496
    uint32_t* wfrag_hi = (uint32_t*)(ws + 116972688);        // 5120 u32 = 20,480
    uint32_t* wfrag_lo = (uint32_t*)(ws + 116993168);        // 5120 u32, ends 117,013,648
    if (ws_size < 117100000) return;  // need ~117.1 MB scratch

    // zero pcnt + ocnt (one contiguous span)
    hipMemsetAsync((char*)pcnt, 0, 2048 + 8, stream);

    dim3 blk(256);
    prep_weights<<<1, blk, 0, stream>>>(Wrel1, Wroot1, b1, Wrel2, Wroot2, b2,
                                        wpack, wfrag_hi, wfrag_lo);

    int bgrid = (3 * EE + TILE - 1) / TILE;   // 367
    bin_edges<<<bgrid, blk, 0, stream>>>(ei_ab, ei_ba, ei_aa, pcnt,
                                         buck_a, buck_b, ocnt, oflow);

    part_sort_agg<<<dim3(NPART, 2), blk, 0, stream>>>(
        pcnt, buck_a, buck_b, x_a, x_b, agg_ba, agg_aa, agg_ab,
        start16_a, start16_b, ktot_a, ktot_b);
    oflow_agg<<<1, blk, 0, stream>>>(ocnt, oflow, x_a, x_b, agg_ba, agg_aa, agg_ab);

    int ngrid = ((NA + 63) / 64) * 2;   // 15626, even = A, odd = B
    node_mfma<<<ngrid, blk, 0, stream>>>(
        x_a, x_b, agg_ba, agg_aa, agg_ab, wpack,
        (const uint4*)wfrag_hi, (const uint4*)wfrag_lo,
        ta0, ta2, tb1, outa, outb);

    int ggrid = (int)(((size_t)(NA + NB) * 8) / 256);  // 31250 exact
    gather_out<<<ggrid, blk, 0, stream>>>(ktot_a, ktot_b, start16_a, start16_b,
                                          buck_a, buck_b, ta0, ta2, tb1,
                                          outa, outb);
    oflow_out<<<1, blk, 0, stream>>>(ocnt, oflow, ta0, ta2, tb1, outa, outb);
}

// Round 12
// 423.698 us; speedup vs baseline: 1.4080x; 1.0096x over previous
//
#include <hip/hip_runtime.h>
#include <hip/hip_bf16.h>
#include <stdint.h>

#define NA 500000
#define NB 500000
#define EE 1000000
#define NPART 245           // partitions per family: ceil(500000/2048)
#define CAPPA 8704          // famA partition cap: mean 8192 + ~5.7 sigma
#define CAPPB 4480          // famB partition cap: mean 4096 + ~6 sigma
#define TILE 8192           // edges per bin_edges block
#define OCAP 2048

typedef __attribute__((ext_vector_type(8))) short bf16x8;
typedef __attribute__((ext_vector_type(4))) float f32x4;
#define MFMA16 __builtin_amdgcn_mfma_f32_16x16x32_bf16

__device__ __forceinline__ uint32_t f2bf(float f) {
    uint32_t b = __builtin_bit_cast(uint32_t, f);
    return (b + 0x7FFFu + ((b >> 16) & 1u)) >> 16;  // RNE
}
__device__ __forceinline__ float bf2f(uint32_t h) {
    return __builtin_bit_cast(float, h << 16);
}

// ---- K1: coarse-bin edges into 490 partitions (fam x dst>>11) ----
__global__ __launch_bounds__(256) void bin_edges(
    const int* __restrict__ ei_ab, const int* __restrict__ ei_ba,
    const int* __restrict__ ei_aa,
    int* __restrict__ pcnt,
    uint32_t* __restrict__ buck_a, uint32_t* __restrict__ buck_b,
    int* __restrict__ ocnt, uint2* __restrict__ oflow) {
    __shared__ int hist[512], start[512], base_[512], cursor[512];
    __shared__ int tsum[256];
    __shared__ uint32_t sbuf[TILE];
    __shared__ uint16_t pid[TILE];
    const int t = threadIdx.x;
    const int tile0 = blockIdx.x * TILE;
    int tcount = 3 * EE - tile0;
    tcount = tcount < 0 ? 0 : (tcount > TILE ? TILE : tcount);

    for (int i = t; i < 512; i += 256) hist[i] = 0;
    __syncthreads();

    // pass A: histogram over partitions
    for (int it = 0; it < TILE / 256; ++it) {
        int gid = tile0 + it * 256 + t;
        if (gid < 3 * EE) {
            int dst, famA;
            if (gid < EE)          { dst = ei_ab[EE + gid]; famA = 0; }
            else if (gid < 2 * EE) { int e = gid - EE;     dst = ei_ba[EE + e]; famA = 1; }
            else                   { int e = gid - 2 * EE; dst = ei_aa[EE + e]; famA = 1; }
            int p = (famA ? 0 : NPART) + (dst >> 11);
            atomicAdd(&hist[p], 1);
        }
    }
    __syncthreads();
    // exclusive scan of hist[512]
    int a = hist[2 * t], b = hist[2 * t + 1];
    tsum[t] = a + b;
    __syncthreads();
    for (int off = 1; off < 256; off <<= 1) {
        int v = tsum[t];
        if (t >= off) v += tsum[t - off];
        __syncthreads();
        tsum[t] = v;
        __syncthreads();
    }
    int ex = tsum[t] - (a + b);
    start[2 * t] = ex;          cursor[2 * t] = ex;
    start[2 * t + 1] = ex + a;  cursor[2 * t + 1] = ex + a;
    __syncthreads();
    for (int p = t; p < 2 * NPART; p += 256) {
        int h = hist[p];
        if (h > 0) base_[p] = atomicAdd(&pcnt[p], h);
    }
    __syncthreads();
    // pass B: place partition-ordered in LDS
    for (int it = 0; it < TILE / 256; ++it) {
        int gid = tile0 + it * 256 + t;
        if (gid < 3 * EE) {
            int dst, src, type, famA;
            if (gid < EE)          { dst = ei_ab[EE + gid]; src = ei_ab[gid]; type = 0; famA = 0; }
            else if (gid < 2 * EE) { int e = gid - EE;     dst = ei_ba[EE + e]; src = ei_ba[e]; type = 0; famA = 1; }
            else                   { int e = gid - 2 * EE; dst = ei_aa[EE + e]; src = ei_aa[e]; type = 1; famA = 1; }
            int p = (famA ? 0 : NPART) + (dst >> 11);
            uint32_t entry = (uint32_t)src | ((uint32_t)type << 19) |
                             ((uint32_t)(dst & 2047) << 20);
            int pos = atomicAdd(&cursor[p], 1);
            sbuf[pos] = entry;
            pid[pos] = (uint16_t)p;
        }
    }
    __syncthreads();
    // flush: consecutive lanes -> consecutive addresses within each run
    for (int i = t; i < tcount; i += 256) {
        int p = pid[i];
        uint32_t e = sbuf[i];
        int rel = base_[p] + (i - start[p]);
        bool isA = p < NPART;
        int cap = isA ? CAPPA : CAPPB;
        if (rel < cap) {
            if (isA) buck_a[(size_t)p * CAPPA + rel] = e;
            else     buck_b[(size_t)(p - NPART) * CAPPB + rel] = e;
        } else {
            int local = (e >> 20) & 2047;
            int dst = ((isA ? p : p - NPART) << 11) + local;
            int type = (e >> 19) & 1;
            int src = e & 0x7FFFF;
            int o = atomicAdd(ocnt, 1);
            if (o < OCAP)
                oflow[o] = make_uint2((uint32_t)dst | ((uint32_t)(isA ? 1 : 0) << 30) |
                                      ((uint32_t)type << 29), (uint32_t)src);
        }
    }
}

// ---- K2: per-partition counting sort (2048 dst-locals) + layer-1 aggs ----
__global__ __launch_bounds__(256) void part_sort_agg(
    const int* __restrict__ pcnt,
    uint32_t* __restrict__ buck_a, uint32_t* __restrict__ buck_b,
    const float* __restrict__ xa, const float* __restrict__ xb,
    float* __restrict__ agg_ba, float* __restrict__ agg_aa,
    float* __restrict__ agg_ab,
    uint16_t* __restrict__ start16_a, uint16_t* __restrict__ start16_b,
    uint16_t* __restrict__ ktot_a, uint16_t* __restrict__ ktot_b) {
    __shared__ uint32_t sorted[CAPPA];
    __shared__ int hist[2048], fill[2048];
    __shared__ int tsum[256];
    const int part = blockIdx.x;
    const int isA = (blockIdx.y == 0);
    const int p = isA ? part : NPART + part;
    const int cap = isA ? CAPPA : CAPPB;
    uint32_t* region = isA ? (buck_a + (size_t)part * CAPPA)
                           : (buck_b + (size_t)part * CAPPB);
    const int t = threadIdx.x;
    int K = pcnt[p];
    K = K < cap ? K : cap;

    for (int i = t; i < 2048; i += 256) hist[i] = 0;
    __syncthreads();
    for (int i = t; i < K; i += 256)
        atomicAdd(&hist[(region[i] >> 20) & 2047], 1);
    __syncthreads();
    int base8 = t * 8;
    int s0 = 0, loc[8];
#pragma unroll
    for (int j = 0; j < 8; ++j) { loc[j] = s0; s0 += hist[base8 + j]; }
    tsum[t] = s0;
    __syncthreads();
    for (int off = 1; off < 256; off <<= 1) {
        int v = tsum[t];
        if (t >= off) v += tsum[t - off];
        __syncthreads();
        tsum[t] = v;
        __syncthreads();
    }
    int ex = tsum[t] - s0;
#pragma unroll
    for (int j = 0; j < 8; ++j) fill[base8 + j] = ex + loc[j];
    __syncthreads();
    {
        uint16_t* s16 = isA ? start16_a : start16_b;
        for (int d = t; d < 2048; d += 256)
            s16[part * 2048 + d] = (uint16_t)fill[d];
        if (t == 0) {
            if (isA) ktot_a[part] = (uint16_t)K;
            else     ktot_b[part] = (uint16_t)K;
        }
    }
    __syncthreads();
    for (int i = t; i < K; i += 256) {
        uint32_t e = region[i];
        int pos = atomicAdd(&fill[(e >> 20) & 2047], 1);
        sorted[pos] = e;
    }
    __syncthreads();
    for (int i = t; i < K; i += 256) region[i] = sorted[i];
    for (int d = t; d < 2048; d += 256) {
        int n = part * 2048 + d;
        if (n >= NA) continue;              // NA == NB
        int end = fill[d], st = end - hist[d];
        if (isA) {
            float sba = 0.f, saa = 0.f;
            for (int i = st; i < end; ++i) {
                uint32_t e = sorted[i];
                int src = e & 0x7FFFF;
                if ((e >> 19) & 1) saa += xa[src];
                else               sba += xb[src];
            }
            agg_ba[n] = sba;
            agg_aa[n] = saa;
        } else {
            float sab = 0.f;
            for (int i = st; i < end; ++i) sab += xa[sorted[i] & 0x7FFFF];
            agg_ab[n] = sab;
        }
    }
}

// ---- K2b: overflow agg fixup (normally ~zero iterations) ----
__global__ __launch_bounds__(256) void oflow_agg(
    const int* __restrict__ ocnt, const uint2* __restrict__ oflow,
    const float* __restrict__ xa, const float* __restrict__ xb,
    float* __restrict__ agg_ba, float* __restrict__ agg_aa,
    float* __restrict__ agg_ab) {
    int n = *ocnt;
    n = n < OCAP ? n : OCAP;
    for (int i = threadIdx.x; i < n; i += 256) {
        uint2 r = oflow[i];
        int dst = r.x & 0x1FFFFFFF;
        int famA = (r.x >> 30) & 1;
        int type = (r.x >> 29) & 1;
        int src = (int)r.y;
        if (famA) {
            if (type) atomicAdd(&agg_aa[dst], xa[src]);
            else      atomicAdd(&agg_ba[dst], xb[src]);
        } else {
            atomicAdd(&agg_ab[dst], xa[src]);
        }
    }
}

// ---- K5: overflow out fixup (last; gather overwrites, so adds come after) ----
__global__ __launch_bounds__(256) void oflow_out(
    const int* __restrict__ ocnt, const uint2* __restrict__ oflow,
    const uint16_t* __restrict__ ta0, const uint16_t* __restrict__ ta2,
    const uint16_t* __restrict__ tb1,
    float* __restrict__ outa, float* __restrict__ outb) {
    int n = *ocnt;
    n = n < OCAP ? n : OCAP;
    for (int i = threadIdx.x; i < n; i += 256) {
        uint2 r = oflow[i];
        int dst = r.x & 0x1FFFFFFF;
        int famA = (r.x >> 30) & 1;
        int type = (r.x >> 29) & 1;
        int src = (int)r.y;
        const uint16_t* tp = famA ? (type ? ta2 : tb1) : ta0;
        float* out = famA ? outa : outb;
        for (int k = 0; k < 32; ++k) {
            float v = __builtin_bit_cast(float,
                          (uint32_t)tp[(size_t)src * 32 + k] << 16);
            atomicAdd(&out[(size_t)dst * 32 + k], v);
        }
    }
}

// ---- K4: gather, 8 lanes per dst node; PURE STORE (root added later) ----
// Unroll-2: two independent random table loads in flight per lane.
__global__ __launch_bounds__(256) void gather_out(
    const uint16_t* __restrict__ ktot_a, const uint16_t* __restrict__ ktot_b,
    const uint16_t* __restrict__ start16_a, const uint16_t* __restrict__ start16_b,
    const uint32_t* __restrict__ buck_a, const uint32_t* __restrict__ buck_b,
    const uint16_t* __restrict__ ta0, const uint16_t* __restrict__ ta2,
    const uint16_t* __restrict__ tb1,
    float* __restrict__ outa, float* __restrict__ outb) {
    int gid = blockIdx.x * 256 + threadIdx.x;   // exactly (NA+NB)*8 threads
    int n3 = gid >> 3;
    int l = gid & 7;
    float4 acc = make_float4(0.f, 0.f, 0.f, 0.f);
    if (n3 < NA) {
        int part = n3 >> 11, local = n3 & 2047;
        int start = start16_a[n3];
        int end = (local == 2047) ? (int)ktot_a[part] : (int)start16_a[n3 + 1];
        const uint32_t* bp = buck_a + (size_t)part * CAPPA;
        int i = start;
        for (; i + 1 < end; i += 2) {
            uint32_t e0 = bp[i], e1 = bp[i + 1];
            int s0 = e0 & 0x7FFFF, s1 = e1 & 0x7FFFF;
            const uint16_t* tp0 = (e0 & (1u << 19)) ? ta2 : tb1;
            const uint16_t* tp1 = (e1 & (1u << 19)) ? ta2 : tb1;
            uint2 u0 = *(const uint2*)(tp0 + (size_t)s0 * 32 + l * 4);
            uint2 u1 = *(const uint2*)(tp1 + (size_t)s1 * 32 + l * 4);
            acc.x += __builtin_bit_cast(float, u0.x << 16);
            acc.y += __builtin_bit_cast(float, u0.x & 0xFFFF0000u);
            acc.z += __builtin_bit_cast(float, u0.y << 16);
            acc.w += __builtin_bit_cast(float, u0.y & 0xFFFF0000u);
            acc.x += __builtin_bit_cast(float, u1.x << 16);
            acc.y += __builtin_bit_cast(float, u1.x & 0xFFFF0000u);
            acc.z += __builtin_bit_cast(float, u1.y << 16);
            acc.w += __builtin_bit_cast(float, u1.y & 0xFFFF0000u);
        }
        if (i < end) {
            uint32_t e = bp[i];
            int src = e & 0x7FFFF;
            const uint16_t* tp = (e & (1u << 19)) ? ta2 : tb1;
            uint2 u = *(const uint2*)(tp + (size_t)src * 32 + l * 4);
            acc.x += __builtin_bit_cast(float, u.x << 16);
            acc.y += __builtin_bit_cast(float, u.x & 0xFFFF0000u);
            acc.z += __builtin_bit_cast(float, u.y << 16);
            acc.w += __builtin_bit_cast(float, u.y & 0xFFFF0000u);
        }
        *(float4*)(outa + (size_t)n3 * 32 + l * 4) = acc;
    } else {
        int n = n3 - NA;
        int part = n >> 11, local = n & 2047;
        int start = start16_b[n];
        int end = (local == 2047) ? (int)ktot_b[part] : (int)start16_b[n + 1];
        const uint32_t* bp = buck_b + (size_t)part * CAPPB;
        int i = start;
        for (; i + 1 < end; i += 2) {
            uint32_t e0 = bp[i], e1 = bp[i + 1];
            int s0 = e0 & 0x7FFFF, s1 = e1 & 0x7FFFF;
            uint2 u0 = *(const uint2*)(ta0 + (size_t)s0 * 32 + l * 4);
            uint2 u1 = *(const uint2*)(ta0 + (size_t)s1 * 32 + l * 4);
            acc.x += __builtin_bit_cast(float, u0.x << 16);
            acc.y += __builtin_bit_cast(float, u0.x & 0xFFFF0000u);
            acc.z += __builtin_bit_cast(float, u0.y << 16);
            acc.w += __builtin_bit_cast(float, u0.y & 0xFFFF0000u);
            acc.x += __builtin_bit_cast(float, u1.x << 16);
            acc.y += __builtin_bit_cast(float, u1.x & 0xFFFF0000u);
            acc.z += __builtin_bit_cast(float, u1.y << 16);
            acc.w += __builtin_bit_cast(float, u1.y & 0xFFFF0000u);
        }
        if (i < end) {
            uint32_t e = bp[i];
            int src = e & 0x7FFFF;
            uint2 u = *(const uint2*)(ta0 + (size_t)src * 32 + l * 4);
            acc.x += __builtin_bit_cast(float, u.x << 16);
            acc.y += __builtin_bit_cast(float, u.x & 0xFFFF0000u);
            acc.z += __builtin_bit_cast(float, u.y << 16);
            acc.w += __builtin_bit_cast(float, u.y & 0xFFFF0000u);
        }
        *(float4*)(outb + (size_t)n * 32 + l * 4) = acc;
    }
}

// ---- prep_weights: uvwc/bias pack + MFMA B-fragment pack (hi/lo split) ----
__global__ __launch_bounds__(256) void prep_weights(
    const float* __restrict__ Wrel1, const float* __restrict__ Wroot1,
    const float* __restrict__ b1,
    const float* __restrict__ Wrel2, const float* __restrict__ Wroot2,
    const float* __restrict__ b2,
    float* __restrict__ wpack,
    uint32_t* __restrict__ whi, uint32_t* __restrict__ wlo) {
    const int t = threadIdx.x;
    if (t < 64) {
        float4* uvA = (float4*)(wpack + 2048);
        float4* uvB = (float4*)(wpack + 2304);
        uvA[t] = make_float4(Wrel1[64 + t], Wrel1[128 + t],
                             Wroot1[64 + t] + Wroot1[128 + t],
                             b1[64 + t] + b1[128 + t]);
        uvB[t] = make_float4(Wrel1[t], 0.f, Wroot1[t], b1[t]);
    }
    if (t >= 64 && t < 96) {
        int o = t - 64;
        wpack[2560 + o] = b2[32 + o] + b2[64 + o];
        wpack[2592 + o] = b2[o];
    }
    for (int w = t; w < 5120; w += 256) {   // 5 mats x 1024 u32
        int j = w & 3;
        int lane = (w >> 2) & 63;
        int s = (w >> 8) & 1;
        int tt = (w >> 9) & 1;
        int m = w >> 10;                    // 0..4
        int k0 = s * 32 + ((lane >> 4) << 3) + 2 * j;
        int col = tt * 16 + (lane & 15);
        int i0 = k0 * 32 + col, i1 = i0 + 32;
        float v0, v1;
        if (m == 0)      { v0 = Wrel2[i0];              v1 = Wrel2[i1]; }
        else if (m == 1) { v0 = Wrel2[4096 + i0];       v1 = Wrel2[4096 + i1]; }
        else if (m == 2) { v0 = Wroot2[2048 + i0] + Wroot2[4096 + i0];
                           v1 = Wroot2[2048 + i1] + Wroot2[4096 + i1]; }
        else if (m == 3) { v0 = Wrel2[2048 + i0];       v1 = Wrel2[2048 + i1]; }
        else             { v0 = Wroot2[i0];             v1 = Wroot2[i1]; }
        uint32_t h0 = f2bf(v0), h1 = f2bf(v1);
        float r0 = v0 - bf2f(h0);
        float r1 = v1 - bf2f(h1);
        whi[w] = h0 | (h1 << 16);
        wlo[w] = f2bf(r0) | (f2bf(r1) << 16);
    }
}

// 3-product split-bf16 pass; accuracy ~fp32.
#define NODE_PASS(MAT, INIT0, INIT1, A0, A1)                                 \
    f32x4 A0 = {(INIT0), (INIT0), (INIT0), (INIT0)};                         \
    f32x4 A1 = {(INIT1), (INIT1), (INIT1), (INIT1)};                         \
    {                                                                        \
        _Pragma("unroll")                                                    \
        for (int s = 0; s < 2; ++s) {                                        \
            bf16x8 bh0 = __builtin_bit_cast(bf16x8, fhi[((MAT)*4 + s)*64 + lane]);     \
            bf16x8 bl0 = __builtin_bit_cast(bf16x8, flo[((MAT)*4 + s)*64 + lane]);     \
            bf16x8 bh1 = __builtin_bit_cast(bf16x8, fhi[((MAT)*4 + 2 + s)*64 + lane]); \
            bf16x8 bl1 = __builtin_bit_cast(bf16x8, flo[((MAT)*4 + 2 + s)*64 + lane]); \
            A0 = MFMA16(ahi[s], bh0, A0, 0, 0, 0);                           \
            A0 = MFMA16(alo[s], bh0, A0, 0, 0, 0);                           \
            A0 = MFMA16(ahi[s], bl0, A0, 0, 0, 0);                           \
            A1 = MFMA16(ahi[s], bh1, A1, 0, 0, 0);                           \
            A1 = MFMA16(alo[s], bh1, A1, 0, 0, 0);                           \
            A1 = MFMA16(ahi[s], bl1, A1, 0, 0, 0);                           \
        }                                                                    \
    }

// bf16 table epilogue: D layout col=lane&15, row=kg*4+r (m89-verified).
#define STORE_TABLE(A0, A1, TP)                                              \
    {                                                                        \
        _Pragma("unroll")                                                    \
        for (int r = 0; r < 4; ++r) {                                        \
            st[wid][kg * 4 + r][mrow]      = (uint16_t)f2bf(A0[r]);          \
            st[wid][kg * 4 + r][16 + mrow] = (uint16_t)f2bf(A1[r]);          \
        }                                                                    \
        int r2 = lane >> 2, cq = lane & 3;                                   \
        int nd = nbase + wid * 16 + r2;                                      \
        if (nd < NA) {                                                       \
            uint4 v = *(const uint4*)&st[wid][r2][cq * 8];                   \
            *((uint4*)((TP) + (size_t)nd * 32) + cq) = v;                    \
        }                                                                    \
    }

// shared h-fragment prologue for both MFMA kernels
#define H_FRAGS                                                              \
    bf16x8 ahi[2], alo[2];                                                   \
    _Pragma("unroll")                                                        \
    for (int s = 0; s < 2; ++s) {                                            \
        _Pragma("unroll")                                                    \
        for (int i = 0; i < 8; ++i) {                                        \
            int k = s * 32 + kg * 8 + i;                                     \
            float4 c4 = uvS[k];                                              \
            float hv = fmaxf(fmaf(i0, c4.x,                                  \
                         fmaf(i1, c4.y, fmaf(i2, c4.z, c4.w))), 0.f);        \
            uint32_t hb = f2bf(hv);                                          \
            float rv = hv - bf2f(hb);                                        \
            ahi[s][i] = (short)hb;                                           \
            alo[s][i] = (short)f2bf(rv);                                     \
        }                                                                    \
    }

// ============ table_mfma: writes bf16 tables only (before gather) ==========
__global__ __launch_bounds__(256) void table_mfma(
    const float* __restrict__ xa, const float* __restrict__ xb,
    const float* __restrict__ s_ba, const float* __restrict__ s_aa,
    const float* __restrict__ s_ab,
    const float* __restrict__ wpack,
    const uint4* __restrict__ fhi, const uint4* __restrict__ flo,
    uint16_t* __restrict__ ta0, uint16_t* __restrict__ ta2,
    uint16_t* __restrict__ tb1) {
    __shared__ float4 uvS[64];
    __shared__ uint16_t st[4][16][32];
    const int tid = threadIdx.x;
    const bool isA = (blockIdx.x & 1) == 0;
    const int nbase = (blockIdx.x >> 1) * 64;
    const int wid = tid >> 6, lane = tid & 63;
    const int mrow = lane & 15, kg = lane >> 4;

    if (tid < 64) uvS[tid] = ((const float4*)(wpack + (isA ? 2048 : 2304)))[tid];
    __syncthreads();

    const int node = nbase + wid * 16 + mrow;
    const bool vin = node < NA;            // NA == NB
    float i0 = 0.f, i1 = 0.f, i2 = 0.f;
    if (isA) {
        if (vin) { i0 = s_ba[node]; i1 = s_aa[node]; i2 = xa[node]; }
    } else {
        if (vin) { i0 = s_ab[node]; i2 = xb[node]; }
    }
    H_FRAGS

    if (isA) {
        { NODE_PASS(0, 0.f, 0.f, p0, p1) STORE_TABLE(p0, p1, ta0) }
        { NODE_PASS(1, 0.f, 0.f, q0, q1) STORE_TABLE(q0, q1, ta2) }
    } else {
        { NODE_PASS(3, 0.f, 0.f, p0, p1) STORE_TABLE(p0, p1, tb1) }
    }
}

// ============ root_mfma: RMW-adds root part + bias into out (after gather) =
__global__ __launch_bounds__(256) void root_mfma(
    const float* __restrict__ xa, const float* __restrict__ xb,
    const float* __restrict__ s_ba, const float* __restrict__ s_aa,
    const float* __restrict__ s_ab,
    const float* __restrict__ wpack,
    const uint4* __restrict__ fhi, const uint4* __restrict__ flo,
    float* __restrict__ outa, float* __restrict__ outb) {
    __shared__ float4 uvS[64];
    const int tid = threadIdx.x;
    const bool isA = (blockIdx.x & 1) == 0;
    const int nbase = (blockIdx.x >> 1) * 64;
    const int wid = tid >> 6, lane = tid & 63;
    const int mrow = lane & 15, kg = lane >> 4;

    if (tid < 64) uvS[tid] = ((const float4*)(wpack + (isA ? 2048 : 2304)))[tid];
    __syncthreads();

    const int node = nbase + wid * 16 + mrow;
    const bool vin = node < NA;            // NA == NB
    float i0 = 0.f, i1 = 0.f, i2 = 0.f;
    if (isA) {
        if (vin) { i0 = s_ba[node]; i1 = s_aa[node]; i2 = xa[node]; }
    } else {
        if (vin) { i0 = s_ab[node]; i2 = xb[node]; }
    }
    const float bb0 = wpack[(isA ? 2560 : 2592) + mrow];
    const float bb1 = wpack[(isA ? 2560 : 2592) + 16 + mrow];
    H_FRAGS

    float* out = isA ? outa : outb;
    if (isA) {
        NODE_PASS(2, bb0, bb1, r0v, r1v)
#pragma unroll
        for (int r = 0; r < 4; ++r) {
            int nd = nbase + wid * 16 + kg * 4 + r;
            if (nd < NA) {
                out[(size_t)nd * 32 + mrow]      += r0v[r];
                out[(size_t)nd * 32 + 16 + mrow] += r1v[r];
            }
        }
    } else {
        NODE_PASS(4, bb0, bb1, r0v, r1v)
#pragma unroll
        for (int r = 0; r < 4; ++r) {
            int nd = nbase + wid * 16 + kg * 4 + r;
            if (nd < NA) {
                out[(size_t)nd * 32 + mrow]      += r0v[r];
                out[(size_t)nd * 32 + 16 + mrow] += r1v[r];
            }
        }
    }
}

extern "C" void kernel_launch(void* const* d_in, const int* in_sizes, int n_in,
                              void* d_out, int out_size, void* d_ws, size_t ws_size,
                              hipStream_t stream) {
    const float* x_a    = (const float*)d_in[0];
    const float* x_b    = (const float*)d_in[1];
    const int*   ei_ab  = (const int*)d_in[2];
    const int*   ei_ba  = (const int*)d_in[3];
    const int*   ei_aa  = (const int*)d_in[4];
    const float* Wrel1  = (const float*)d_in[5];
    const float* Wroot1 = (const float*)d_in[6];
    const float* b1     = (const float*)d_in[7];
    const float* Wrel2  = (const float*)d_in[8];
    const float* Wroot2 = (const float*)d_in[9];
    const float* b2     = (const float*)d_in[10];

    float* outa = (float*)d_out;                       // [NA,32]
    float* outb = (float*)d_out + (size_t)NA * 32;     // [NB,32]

    char* ws = (char*)d_ws;
    // Layout (bytes):
    uint32_t* buck_a   = (uint32_t*)(ws);                    // 245*8704*4 = 8,529,920
    uint32_t* buck_b   = (uint32_t*)(ws + 8529920);          // 245*4480*4 = 4,390,400
    float*    agg_ba   = (float*)(ws + 12920320);            // NA floats
    float*    agg_aa   = (float*)(ws + 14920320);            // NA floats
    float*    agg_ab   = (float*)(ws + 16920320);            // NB floats
    uint16_t* ta0      = (uint16_t*)(ws + 18920320);         // NA*32 bf16
    uint16_t* ta2      = (uint16_t*)(ws + 50920320);         // NA*32 bf16
    uint16_t* tb1      = (uint16_t*)(ws + 82920320);         // NB*32 bf16
    uint16_t* start16_a= (uint16_t*)(ws + 114920320);        // 245*2048 u16 = 1,003,520
    uint16_t* start16_b= (uint16_t*)(ws + 115923840);        // 245*2048 u16
    uint16_t* ktot_a   = (uint16_t*)(ws + 116927360);        // 245 u16 (pad 8192)
    uint16_t* ktot_b   = (uint16_t*)(ws + 116935552);        // 245 u16 (pad 8192)
    int*      pcnt     = (int*)(ws + 116943744);             // 512 int = 2,048
    int*      ocnt     = (int*)(ws + 116945792);             // 1 int (+4 pad)
    uint2*    oflow    = (uint2*)(ws + 116945800);           // 2048 uint2 = 16,384
    float*    wpack    = (float*)(ws + 116962192);           // 2624 floats = 10,496
    uint32_t* wfrag_hi = (uint32_t*)(ws + 116972688);        // 5120 u32 = 20,480
    uint32_t* wfrag_lo = (uint32_t*)(ws + 116993168);        // 5120 u32, ends 117,013,648
    if (ws_size < 117100000) return;  // need ~117.1 MB scratch

    // zero pcnt + ocnt (one contiguous span)
    hipMemsetAsync((char*)pcnt, 0, 2048 + 8, stream);

    dim3 blk(256);
    prep_weights<<<1, blk, 0, stream>>>(Wrel1, Wroot1, b1, Wrel2, Wroot2, b2,
                                        wpack, wfrag_hi, wfrag_lo);

    int bgrid = (3 * EE + TILE - 1) / TILE;   // 367
    bin_edges<<<bgrid, blk, 0, stream>>>(ei_ab, ei_ba, ei_aa, pcnt,
                                         buck_a, buck_b, ocnt, oflow);

    part_sort_agg<<<dim3(NPART, 2), blk, 0, stream>>>(
        pcnt, buck_a, buck_b, x_a, x_b, agg_ba, agg_aa, agg_ab,
        start16_a, start16_b, ktot_a, ktot_b);
    oflow_agg<<<1, blk, 0, stream>>>(ocnt, oflow, x_a, x_b, agg_ba, agg_aa, agg_ab);

    int ngrid = ((NA + 63) / 64) * 2;   // 15626, even = A, odd = B
    table_mfma<<<ngrid, blk, 0, stream>>>(
        x_a, x_b, agg_ba, agg_aa, agg_ab, wpack,
        (const uint4*)wfrag_hi, (const uint4*)wfrag_lo,
        ta0, ta2, tb1);

    int ggrid = (int)(((size_t)(NA + NB) * 8) / 256);  // 31250 exact
    gather_out<<<ggrid, blk, 0, stream>>>(ktot_a, ktot_b, start16_a, start16_b,
                                          buck_a, buck_b, ta0, ta2, tb1,
                                          outa, outb);

    root_mfma<<<ngrid, blk, 0, stream>>>(
        x_a, x_b, agg_ba, agg_aa, agg_ab, wpack,
        (const uint4*)wfrag_hi, (const uint4*)wfrag_lo,
        outa, outb);

    oflow_out<<<1, blk, 0, stream>>>(ocnt, oflow, ta0, ta2, tb1, outa, outb);
}